// Round 3
// baseline (391.733 us; speedup 1.0000x reference)
//
#include <hip/hip_runtime.h>
#include <math.h>

#define N_NODES   100000
#define N_EDGES   1600000
#define ETOT      1700000   // edges + self loops
#define F_IN      100
#define HEADS     3
#define HEAD_DIM  64
#define HIDDEN    192
#define NUM_GRAPHS 128
#define NUM_CLASSES 2
#define WT_COLS   208       // 13 col-tiles of 16 (192 h + 6 att + pad)
#define KPAD      128       // K padded to 4 chunks of 32
#define NCHUNK    ((ETOT + 1023) / 1024)   // 1661 edge-chunks of 1024
#define DRANGE    (N_NODES / 8)            // 12500 dsts per XCD class
#define NGEMM     (N_NODES / 32)           // 3125 gemm tiles (32-node tiles)
#define GEMM_BLKS 1024      // persistent gemm blocks (grid-stride over tiles)
#define SCAT_BLKS 2048      // persistent scatter blocks (256 per XCD class)
#define OSTRIDE   200       // LDS out-stage row stride (shorts)
#define GAGG      16        // nodes per k_aggr block
#define CAP       64        // bucket capacity (max degree ~45 for Pois(17))

typedef unsigned short ushort_t;
typedef __attribute__((ext_vector_type(8))) short short8;
typedef __attribute__((ext_vector_type(4))) float floatx4;

// ---- ordered-uint encoding for float atomicMax (handles negatives) ----
__device__ __forceinline__ unsigned f2ord(float f) {
    unsigned u = __float_as_uint(f);
    return (u & 0x80000000u) ? ~u : (u | 0x80000000u);
}
__device__ __forceinline__ float ord2f(unsigned u) {
    return __uint_as_float((u & 0x80000000u) ? (u & 0x7fffffffu) : ~u);
}
__device__ __forceinline__ unsigned bf16rn(float f) {   // RTNE f32 -> bf16 bits
    unsigned u = __float_as_uint(f);
    return (u + 0x7fffu + ((u >> 16) & 1u)) >> 16;
}
// SGPR broadcasts (SALU/VALU, no LDS pipe)
__device__ __forceinline__ int rl_i(int v, int l) {
    return __builtin_amdgcn_readlane(v, l);
}
__device__ __forceinline__ float rl_f(float v, int l) {
    return __uint_as_float((unsigned)__builtin_amdgcn_readlane((int)__float_as_uint(v), l));
}
// direction-independent DPP butterfly add (xor1 / xor2 / xor8 on VALU pipe)
template<int CTRL>
__device__ __forceinline__ float bfly(float v) {
    int t = __builtin_amdgcn_update_dpp(0, (int)__float_as_uint(v), CTRL, 0xF, 0xF, false);
    return v + __uint_as_float((unsigned)t);
}
#define DPP_XOR1 0xB1   // quad_perm [1,0,3,2]
#define DPP_XOR2 0x4E   // quad_perm [2,3,0,1]
#define DPP_XOR8 0x128  // row_ror:8 within 16-lane row == xor 8

// ---- K0: prep — build transposed hi/lo bf16 W (26 blocks x 8 cols) ----
__global__ __launch_bounds__(256) void k_prep(
        const float* __restrict__ W, const float* __restrict__ att_src,
        const float* __restrict__ att_dst,
        ushort_t* __restrict__ WT_hi, ushort_t* __restrict__ WT_lo) {
    const int c0 = blockIdx.x * 8;
    const int t = threadIdx.x;
    __shared__ float wsv_s[F_IN * 6];
    if (c0 < HIDDEN + 6 && c0 + 8 > HIDDEN) {      // this block covers att cols
        for (int p = t; p < F_IN * 6; p += 256) {
            int k = p / 6, j = p % 6;
            const float* a = (j < 3) ? att_src : att_dst;
            int hh = j % 3;
            float s = 0.f;
            for (int c = 0; c < HEAD_DIM; c++)
                s += W[k * HIDDEN + hh * HEAD_DIM + c] * a[hh * HEAD_DIM + c];
            wsv_s[p] = s;
        }
        __syncthreads();
    }
    for (int idx = t; idx < 8 * KPAD; idx += 256) {
        int col = c0 + (idx >> 7), k = idx & (KPAD - 1);
        float v = 0.f;
        if (k < F_IN) {
            if (col < HIDDEN) v = W[k * HIDDEN + col];
            else if (col < HIDDEN + 6) v = wsv_s[k * 6 + (col - HIDDEN)];
        }
        unsigned hi = bf16rn(v);
        WT_hi[col * KPAD + k] = (ushort_t)hi;
        float lo = v - __uint_as_float(hi << 16);
        WT_lo[col * KPAD + k] = (ushort_t)bf16rn(lo);
    }
}

// ---- K1: MEGA = persistent gemm blocks ∪ persistent scatter blocks ----
// R3: grid-stride. 16413 tiny WGs -> 3072 persistent WGs (dispatch-rate
// hypothesis: all pipes <16% busy, retire rate pinned at ~109 WG/us).
// Inner bodies byte-identical to R2; only the looping changed.
__global__ __launch_bounds__(256) void k_mega(
        const float* __restrict__ x,
        const ushort_t* __restrict__ WT_hi, const ushort_t* __restrict__ WT_lo,
        ushort_t* __restrict__ hb,
        float* __restrict__ asrc, float* __restrict__ adst,
        const int* __restrict__ ei, int* __restrict__ count,
        int* __restrict__ srcs) {
    __shared__ ushort_t lds[32 * 136 * 2];        // 17408 B; reused for out-stage
    const int tid = threadIdx.x;

    if (blockIdx.x >= GEMM_BLKS) {
        // ---------------- bucket-scatter body (persistent) ----------------
        const int s = blockIdx.x - GEMM_BLKS;     // 1024%8==0: cls==blockIdx%8
        const int cls = s & 7;                    // XCD class (round-robin)
        const int dlo = cls * DRANGE, dhi = dlo + DRANGE;
        for (int chunk = s >> 3; chunk < NCHUNK; chunk += SCAT_BLKS / 8) {
            const int base = chunk * 1024 + tid;
            int d4[4], s4[4];
#pragma unroll
            for (int q = 0; q < 4; q++) {         // hoisted coalesced loads
                int j = base + q * 256;
                if (j >= ETOT) { d4[q] = -1; s4[q] = 0; continue; }
                d4[q] = (j < N_EDGES) ? ei[N_EDGES + j] : (j - N_EDGES);
                s4[q] = (j < N_EDGES) ? ei[j] : d4[q];
            }
#pragma unroll
            for (int q = 0; q < 4; q++) {
                int d = d4[q];
                if (d < dlo || d >= dhi) continue;
                int pos = atomicAdd(&count[d], 1);
                if (pos < CAP) srcs[d * CAP + pos] = s4[q];
            }
        }
        return;
    }

    // ---------------- gemm body (persistent, 32-node M-tiles) ----------------
    ushort_t* xs_hi = lds;
    ushort_t* xs_lo = lds + 32 * 136;
    const int wid = tid >> 6, l = tid & 63;
    const int row16 = l & 15, g = l >> 4;          // col-in-tile, k-quad
    const int NT = (wid == 3) ? 4 : 3;
    const int t0 = wid * 3;

    for (int tile = blockIdx.x; tile < NGEMM; tile += GEMM_BLKS) {
        const int base = tile * 32;
        for (int idx = tid; idx < 32 * KPAD; idx += 256) {
            int row = idx >> 7, k = idx & (KPAD - 1);
            float v = (k < F_IN) ? x[(base + row) * F_IN + k] : 0.f;
            unsigned hi = bf16rn(v);
            xs_hi[row * 136 + k] = (ushort_t)hi;
            float lo = v - __uint_as_float(hi << 16);
            xs_lo[row * 136 + k] = (ushort_t)bf16rn(lo);
        }
        __syncthreads();

        floatx4 acc[2][4];
#pragma unroll
        for (int m = 0; m < 2; m++)
#pragma unroll
            for (int i = 0; i < 4; i++) acc[m][i] = (floatx4)0.f;

#pragma unroll
        for (int c = 0; c < 4; c++) {              // K chunks of 32
            const int ke = g * 8 + c * 32;
            short8 ah0 = *(const short8*)(xs_hi + row16 * 136 + ke);
            short8 al0 = *(const short8*)(xs_lo + row16 * 136 + ke);
            short8 ah1 = *(const short8*)(xs_hi + (16 + row16) * 136 + ke);
            short8 al1 = *(const short8*)(xs_lo + (16 + row16) * 136 + ke);
#pragma unroll
            for (int ti = 0; ti < 4; ti++) {
                if (ti >= NT) break;
                const int col = (t0 + ti) * 16 + row16;
                short8 bh = *(const short8*)(WT_hi + col * KPAD + ke);
                short8 bl = *(const short8*)(WT_lo + col * KPAD + ke);
                acc[0][ti] = __builtin_amdgcn_mfma_f32_16x16x32_bf16(ah0, bh, acc[0][ti], 0, 0, 0);
                acc[0][ti] = __builtin_amdgcn_mfma_f32_16x16x32_bf16(ah0, bl, acc[0][ti], 0, 0, 0);
                acc[0][ti] = __builtin_amdgcn_mfma_f32_16x16x32_bf16(al0, bh, acc[0][ti], 0, 0, 0);
                acc[1][ti] = __builtin_amdgcn_mfma_f32_16x16x32_bf16(ah1, bh, acc[1][ti], 0, 0, 0);
                acc[1][ti] = __builtin_amdgcn_mfma_f32_16x16x32_bf16(ah1, bl, acc[1][ti], 0, 0, 0);
                acc[1][ti] = __builtin_amdgcn_mfma_f32_16x16x32_bf16(al1, bh, acc[1][ti], 0, 0, 0);
            }
        }

        __syncthreads();                           // xs dead; reuse lds for out-stage

        // stage h tiles to LDS (C/D layout col=row16, row=g*4+r; m89-verified)
#pragma unroll
        for (int ti = 0; ti < 4; ti++) {
            if (ti >= NT) break;
            const int tile_c = t0 + ti;
            if (tile_c < 12) {
#pragma unroll
                for (int m = 0; m < 2; m++)
#pragma unroll
                    for (int r = 0; r < 4; r++) {
                        int node = m * 16 + g * 4 + r;
                        lds[node * OSTRIDE + tile_c * 16 + row16] =
                            (ushort_t)bf16rn(acc[m][ti][r]);
                    }
            } else if (row16 < 6) {                // att cols 192..197
#pragma unroll
                for (int m = 0; m < 2; m++)
#pragma unroll
                    for (int r = 0; r < 4; r++) {
                        int node = base + m * 16 + g * 4 + r;
                        if (row16 < 3) asrc[node * HEADS + row16] = acc[m][ti][r];
                        else           adst[node * HEADS + (row16 - 3)] = acc[m][ti][r];
                    }
            }
        }
        __syncthreads();

        // coalesced copy-out: 32 nodes x 384B = 768 uint4, contiguous in hb
        uint4* hb4 = (uint4*)(hb + (size_t)base * HIDDEN);
#pragma unroll
        for (int i = 0; i < 3; i++) {
            int q = tid + i * 256;                 // 0..767
            int row = q / 24, c8 = q % 24;
            hb4[q] = *(const uint4*)(lds + row * OSTRIDE + c8 * 8);
        }
        __syncthreads();                           // protect lds before next stage
    }
}

// ---- K5: softmax-aggregate + bias + leaky_relu + FUSED max-pool ----
// 8-way-parallel gather (8 sources x 8 channel-octets per wave, full MLP),
// all reductions on VALU (DPP butterflies), broadcasts via readlane.
__global__ __launch_bounds__(192) void k_aggr(const int* __restrict__ count,
        const int* __restrict__ srcs, const float* __restrict__ asrc,
        const float* __restrict__ adst, const ushort_t* __restrict__ hb,
        const float* __restrict__ bias, const int* __restrict__ batch,
        unsigned* __restrict__ pooled) {
    __shared__ float sm[HIDDEN];
    const int n0 = blockIdx.x * GAGG;
    const int tid = threadIdx.x;
    const int head = tid >> 6, lane = tid & 63;
    // source-slot = lane bits {0,1,3}; channel-octet = lane bits {2,4,5}
    const int srci = (lane & 3) | ((lane >> 1) & 4);
    const int slot = ((lane >> 2) & 1) | ((lane >> 3) & 6);
    const char* hbase = (const char*)hb + head * 128 + slot * 16;
    const int c0 = head * HEAD_DIM + slot * 8;

    // per-block preloads (amortized over GAGG nodes)
    int cntv = (lane < GAGG) ? count[n0 + lane] : 0;
    int bgv  = (lane < GAGG) ? batch[n0 + lane] : 0;
    float adv = (lane < GAGG * HEADS) ? adst[n0 * HEADS + lane] : 0.f;
    float bv[8];
#pragma unroll
    for (int k = 0; k < 8; k++) bv[k] = bias[c0 + k];

    float vmax[8];
#pragma unroll
    for (int k = 0; k < 8; k++) vmax[k] = -INFINITY;
    int curg = rl_i(bgv, 0);

    for (int g = 0; g < GAGG; g++) {
        const int gg = rl_i(bgv, g);           // uniform (batch sorted)
        if (gg != curg) {                      // block-uniform graph boundary
            if ((lane & 11) == 0) {            // one owner lane per octet
#pragma unroll
                for (int k = 0; k < 8; k++) sm[c0 + k] = vmax[k];
            }
            __syncthreads();
            atomicMax(&pooled[curg * HIDDEN + tid], f2ord(sm[tid]));
            __syncthreads();
#pragma unroll
            for (int k = 0; k < 8; k++) vmax[k] = -INFINITY;
            curg = gg;
        }

        int cnt = rl_i(cntv, g);
        if (cnt > CAP) cnt = CAP;
        const float ad = rl_f(adv, g * HEADS + head);
        const int n = n0 + g;

        int s = srcs[n * CAP + lane];          // one coalesced 256B bucket read
        float myexp = 0.f; int myoff = 0;
        if (lane < cnt) {
            float e = asrc[s * HEADS + head] + ad;
            e = (e > 0.f) ? e : 0.2f * e;      // leaky_relu slope 0.2
            myexp = expf(e);                   // max-free softmax numerator
            myoff = s * (HIDDEN * 2);
        }

        float acc[8];
#pragma unroll
        for (int k = 0; k < 8; k++) acc[k] = 0.f;
        float dpart = 0.f;
        int groups = (cnt + 7) >> 3;
#pragma unroll 2
        for (int j = 0; j < groups; j++) {
            int sl = j * 8 + srci;
            float a   = __shfl(myexp, sl);     // 0 for padded edges
            int   off = __shfl(myoff, sl);
            uint4 u = *(const uint4*)(hbase + off);
            acc[0] += a * __uint_as_float(u.x << 16);
            acc[1] += a * __uint_as_float(u.x & 0xffff0000u);
            acc[2] += a * __uint_as_float(u.y << 16);
            acc[3] += a * __uint_as_float(u.y & 0xffff0000u);
            acc[4] += a * __uint_as_float(u.z << 16);
            acc[5] += a * __uint_as_float(u.z & 0xffff0000u);
            acc[6] += a * __uint_as_float(u.w << 16);
            acc[7] += a * __uint_as_float(u.w & 0xffff0000u);
            dpart += a;
        }

        // VALU butterfly over lane bits {0,1,3}: sums the 8 source-slots
        dpart = bfly<DPP_XOR1>(dpart);
        dpart = bfly<DPP_XOR2>(dpart);
        dpart = bfly<DPP_XOR8>(dpart);
#pragma unroll
        for (int k = 0; k < 8; k++) {
            acc[k] = bfly<DPP_XOR1>(acc[k]);
            acc[k] = bfly<DPP_XOR2>(acc[k]);
            acc[k] = bfly<DPP_XOR8>(acc[k]);
        }

        const float inv = 1.f / dpart;
#pragma unroll
        for (int k = 0; k < 8; k++) {          // all lanes (redundant, branchless)
            float v = acc[k] * inv + bv[k];
            v = (v > 0.f) ? v : 0.01f * v;     // F.leaky_relu slope 0.01
            vmax[k] = fmaxf(vmax[k], v);
        }
    }

    // final flush
    if ((lane & 11) == 0) {
#pragma unroll
        for (int k = 0; k < 8; k++) sm[c0 + k] = vmax[k];
    }
    __syncthreads();
    atomicMax(&pooled[curg * HIDDEN + tid], f2ord(sm[tid]));
}

// ---- K6: classifier, block per graph, lane-parallel dot + reduce ----
__global__ __launch_bounds__(64) void k_cls(const unsigned* __restrict__ pooled,
        const float* __restrict__ clsW, const float* __restrict__ clsb,
        float* __restrict__ out) {
    const int g = blockIdx.x, lane = threadIdx.x;
    float s0 = 0.f, s1 = 0.f;
#pragma unroll
    for (int i = 0; i < 3; i++) {
        int f = i * 64 + lane;
        float pv = ord2f(pooled[g * HIDDEN + f]);
        s0 += pv * clsW[f * NUM_CLASSES];
        s1 += pv * clsW[f * NUM_CLASSES + 1];
    }
#pragma unroll
    for (int m = 1; m < 64; m <<= 1) {
        s0 += __shfl_xor(s0, m);
        s1 += __shfl_xor(s1, m);
    }
    if (lane == 0) {
        out[g * NUM_CLASSES]     = s0 + clsb[0];
        out[g * NUM_CLASSES + 1] = s1 + clsb[1];
    }
}

extern "C" void kernel_launch(void* const* d_in, const int* in_sizes, int n_in,
                              void* d_out, int out_size, void* d_ws, size_t ws_size,
                              hipStream_t stream) {
    const float* x       = (const float*)d_in[0];
    const int*   ei      = (const int*)d_in[1];   // [2, N_EDGES] flat
    const int*   batch   = (const int*)d_in[2];
    const float* W       = (const float*)d_in[3];
    const float* att_src = (const float*)d_in[4];
    const float* att_dst = (const float*)d_in[5];
    const float* bias    = (const float*)d_in[6];
    const float* clsW    = (const float*)d_in[7];
    const float* clsb    = (const float*)d_in[8];
    float* out = (float*)d_out;

    char* p = (char*)d_ws;
    auto alloc = [&](size_t bytes) {
        char* r = p; p += (bytes + 255) & ~size_t(255); return r;
    };
    ushort_t* hb     = (ushort_t*)alloc(sizeof(ushort_t) * N_NODES * HIDDEN);
    float*    asrc   = (float*)   alloc(sizeof(float) * N_NODES * HEADS);
    float*    adst   = (float*)   alloc(sizeof(float) * N_NODES * HEADS);
    int*      count  = (int*)     alloc(sizeof(int) * N_NODES);
    int*      srcs   = (int*)     alloc(sizeof(int) * (size_t)N_NODES * CAP);
    ushort_t* WT_hi  = (ushort_t*)alloc(sizeof(ushort_t) * WT_COLS * KPAD);
    ushort_t* WT_lo  = (ushort_t*)alloc(sizeof(ushort_t) * WT_COLS * KPAD);
    unsigned* pooled = (unsigned*)alloc(sizeof(unsigned) * NUM_GRAPHS * HIDDEN);

    hipMemsetAsync(count, 0, sizeof(int) * N_NODES, stream);
    hipMemsetAsync(pooled, 0, sizeof(unsigned) * NUM_GRAPHS * HIDDEN, stream);

    k_prep<<<WT_COLS / 8, 256, 0, stream>>>(W, att_src, att_dst, WT_hi, WT_lo);
    k_mega<<<GEMM_BLKS + SCAT_BLKS, 256, 0, stream>>>(x, WT_hi, WT_lo, hb, asrc, adst,
                                                      ei, count, srcs);
    k_aggr<<<N_NODES / GAGG, 192, 0, stream>>>(count, srcs, asrc, adst, hb, bias,
                                               batch, pooled);
    k_cls<<<NUM_GRAPHS, 64, 0, stream>>>(pooled, clsW, clsb, out);
}

// Round 4
// 375.440 us; speedup vs baseline: 1.0434x; 1.0434x over previous
//
#include <hip/hip_runtime.h>
#include <math.h>

#define N_NODES   100000
#define N_EDGES   1600000
#define ETOT      1700000   // edges + self loops
#define F_IN      100
#define HEADS     3
#define HEAD_DIM  64
#define HIDDEN    192
#define NUM_GRAPHS 128
#define NUM_CLASSES 2
#define WT_COLS   208       // 13 col-tiles of 16 (192 h + 6 att + pad)
#define KPAD      128       // K padded to 4 chunks of 32
#define NCHUNK    ((ETOT + 1023) / 1024)   // 1661 edge-chunks of 1024
#define DRANGE    (N_NODES / 8)            // 12500 dsts per XCD class
#define NGEMM     (N_NODES / 32)           // 3125 gemm tiles (32-node tiles)
#define SCAT_BLKS 2048      // persistent scatter blocks (256 per XCD class)
#define OSTRIDE   200       // LDS out-stage row stride (shorts)
#define GAGG      16        // nodes per k_aggr block
#define CAP       64        // bucket capacity (max degree ~45 for Pois(17))

typedef unsigned short ushort_t;
typedef __attribute__((ext_vector_type(8))) short short8;
typedef __attribute__((ext_vector_type(4))) float floatx4;

// ---- ordered-uint encoding for float atomicMax (handles negatives) ----
__device__ __forceinline__ unsigned f2ord(float f) {
    unsigned u = __float_as_uint(f);
    return (u & 0x80000000u) ? ~u : (u | 0x80000000u);
}
__device__ __forceinline__ float ord2f(unsigned u) {
    return __uint_as_float((u & 0x80000000u) ? (u & 0x7fffffffu) : ~u);
}
__device__ __forceinline__ unsigned bf16rn(float f) {   // RTNE f32 -> bf16 bits
    unsigned u = __float_as_uint(f);
    return (u + 0x7fffu + ((u >> 16) & 1u)) >> 16;
}
// SGPR broadcasts (SALU/VALU, no LDS pipe)
__device__ __forceinline__ int rl_i(int v, int l) {
    return __builtin_amdgcn_readlane(v, l);
}
__device__ __forceinline__ float rl_f(float v, int l) {
    return __uint_as_float((unsigned)__builtin_amdgcn_readlane((int)__float_as_uint(v), l));
}
// direction-independent DPP butterfly add (xor1 / xor2 / xor8 on VALU pipe)
template<int CTRL>
__device__ __forceinline__ float bfly(float v) {
    int t = __builtin_amdgcn_update_dpp(0, (int)__float_as_uint(v), CTRL, 0xF, 0xF, false);
    return v + __uint_as_float((unsigned)t);
}
#define DPP_XOR1 0xB1   // quad_perm [1,0,3,2]
#define DPP_XOR2 0x4E   // quad_perm [2,3,0,1]
#define DPP_XOR8 0x128  // row_ror:8 within 16-lane row == xor 8

// ---- K0: prep — build transposed hi/lo bf16 W (26 blocks x 8 cols) ----
__global__ __launch_bounds__(256) void k_prep(
        const float* __restrict__ W, const float* __restrict__ att_src,
        const float* __restrict__ att_dst,
        ushort_t* __restrict__ WT_hi, ushort_t* __restrict__ WT_lo) {
    const int c0 = blockIdx.x * 8;
    const int t = threadIdx.x;
    __shared__ float wsv_s[F_IN * 6];
    if (c0 < HIDDEN + 6 && c0 + 8 > HIDDEN) {      // this block covers att cols
        for (int p = t; p < F_IN * 6; p += 256) {
            int k = p / 6, j = p % 6;
            const float* a = (j < 3) ? att_src : att_dst;
            int hh = j % 3;
            float s = 0.f;
            for (int c = 0; c < HEAD_DIM; c++)
                s += W[k * HIDDEN + hh * HEAD_DIM + c] * a[hh * HEAD_DIM + c];
            wsv_s[p] = s;
        }
        __syncthreads();
    }
    for (int idx = t; idx < 8 * KPAD; idx += 256) {
        int col = c0 + (idx >> 7), k = idx & (KPAD - 1);
        float v = 0.f;
        if (k < F_IN) {
            if (col < HIDDEN) v = W[k * HIDDEN + col];
            else if (col < HIDDEN + 6) v = wsv_s[k * 6 + (col - HIDDEN)];
        }
        unsigned hi = bf16rn(v);
        WT_hi[col * KPAD + k] = (ushort_t)hi;
        float lo = v - __uint_as_float(hi << 16);
        WT_lo[col * KPAD + k] = (ushort_t)bf16rn(lo);
    }
}

// ---- K1a: GEMM (R2-identical body, non-persistent: VGPR ~48, 9 WG/CU) ----
__global__ __launch_bounds__(256) void k_gemm(
        const float* __restrict__ x,
        const ushort_t* __restrict__ WT_hi, const ushort_t* __restrict__ WT_lo,
        ushort_t* __restrict__ hb,
        float* __restrict__ asrc, float* __restrict__ adst) {
    __shared__ ushort_t lds[32 * 136 * 2];        // 17408 B; reused for out-stage
    const int tid = threadIdx.x;

    ushort_t* xs_hi = lds;
    ushort_t* xs_lo = lds + 32 * 136;
    const int base = blockIdx.x * 32;
    for (int idx = tid; idx < 32 * KPAD; idx += 256) {
        int row = idx >> 7, k = idx & (KPAD - 1);
        float v = (k < F_IN) ? x[(base + row) * F_IN + k] : 0.f;
        unsigned hi = bf16rn(v);
        xs_hi[row * 136 + k] = (ushort_t)hi;
        float lo = v - __uint_as_float(hi << 16);
        xs_lo[row * 136 + k] = (ushort_t)bf16rn(lo);
    }
    __syncthreads();

    const int wid = tid >> 6, l = tid & 63;
    const int row16 = l & 15, g = l >> 4;          // col-in-tile, k-quad
    const int NT = (wid == 3) ? 4 : 3;
    const int t0 = wid * 3;

    floatx4 acc[2][4];
#pragma unroll
    for (int m = 0; m < 2; m++)
#pragma unroll
        for (int i = 0; i < 4; i++) acc[m][i] = (floatx4)0.f;

#pragma unroll
    for (int c = 0; c < 4; c++) {                  // K chunks of 32
        const int ke = g * 8 + c * 32;
        short8 ah0 = *(const short8*)(xs_hi + row16 * 136 + ke);
        short8 al0 = *(const short8*)(xs_lo + row16 * 136 + ke);
        short8 ah1 = *(const short8*)(xs_hi + (16 + row16) * 136 + ke);
        short8 al1 = *(const short8*)(xs_lo + (16 + row16) * 136 + ke);
#pragma unroll
        for (int ti = 0; ti < 4; ti++) {
            if (ti >= NT) break;
            const int col = (t0 + ti) * 16 + row16;
            short8 bh = *(const short8*)(WT_hi + col * KPAD + ke);
            short8 bl = *(const short8*)(WT_lo + col * KPAD + ke);
            acc[0][ti] = __builtin_amdgcn_mfma_f32_16x16x32_bf16(ah0, bh, acc[0][ti], 0, 0, 0);
            acc[0][ti] = __builtin_amdgcn_mfma_f32_16x16x32_bf16(ah0, bl, acc[0][ti], 0, 0, 0);
            acc[0][ti] = __builtin_amdgcn_mfma_f32_16x16x32_bf16(al0, bh, acc[0][ti], 0, 0, 0);
            acc[1][ti] = __builtin_amdgcn_mfma_f32_16x16x32_bf16(ah1, bh, acc[1][ti], 0, 0, 0);
            acc[1][ti] = __builtin_amdgcn_mfma_f32_16x16x32_bf16(ah1, bl, acc[1][ti], 0, 0, 0);
            acc[1][ti] = __builtin_amdgcn_mfma_f32_16x16x32_bf16(al1, bh, acc[1][ti], 0, 0, 0);
        }
    }

    __syncthreads();                               // xs dead; reuse lds for out-stage

    // stage h tiles to LDS (C/D layout col=row16, row=g*4+r; m89-verified)
#pragma unroll
    for (int ti = 0; ti < 4; ti++) {
        if (ti >= NT) break;
        const int tile = t0 + ti;
        if (tile < 12) {
#pragma unroll
            for (int m = 0; m < 2; m++)
#pragma unroll
                for (int r = 0; r < 4; r++) {
                    int node = m * 16 + g * 4 + r;
                    lds[node * OSTRIDE + tile * 16 + row16] =
                        (ushort_t)bf16rn(acc[m][ti][r]);
                }
        } else if (row16 < 6) {                    // att cols 192..197
#pragma unroll
            for (int m = 0; m < 2; m++)
#pragma unroll
                for (int r = 0; r < 4; r++) {
                    int node = base + m * 16 + g * 4 + r;
                    if (row16 < 3) asrc[node * HEADS + row16] = acc[m][ti][r];
                    else           adst[node * HEADS + (row16 - 3)] = acc[m][ti][r];
                }
        }
    }
    __syncthreads();

    // coalesced copy-out: 32 nodes x 384B = 768 uint4, contiguous in hb
    uint4* hb4 = (uint4*)(hb + (size_t)base * HIDDEN);
#pragma unroll
    for (int i = 0; i < 3; i++) {
        int q = tid + i * 256;                     // 0..767
        int row = q / 24, c8 = q % 24;
        hb4[q] = *(const uint4*)(lds + row * OSTRIDE + c8 * 8);
    }
}

// ---- K1b: bucket-scatter, persistent grid-stride (no LDS, ~20 VGPR) ----
// 2048 WGs = 8 WG/CU, full occupancy; kills the WG-dispatch-rate term.
// Inner body identical to R2. cls = s&7 preserves XCD class round-robin.
__global__ __launch_bounds__(256) void k_scat(
        const int* __restrict__ ei, int* __restrict__ count,
        int* __restrict__ srcs) {
    const int tid = threadIdx.x;
    const int s = blockIdx.x;
    const int cls = s & 7;                        // XCD class (round-robin)
    const int dlo = cls * DRANGE, dhi = dlo + DRANGE;
    for (int chunk = s >> 3; chunk < NCHUNK; chunk += SCAT_BLKS / 8) {
        const int base = chunk * 1024 + tid;
        int d4[4], s4[4];
#pragma unroll
        for (int q = 0; q < 4; q++) {             // hoisted coalesced loads
            int j = base + q * 256;
            if (j >= ETOT) { d4[q] = -1; s4[q] = 0; continue; }
            d4[q] = (j < N_EDGES) ? ei[N_EDGES + j] : (j - N_EDGES);
            s4[q] = (j < N_EDGES) ? ei[j] : d4[q];
        }
#pragma unroll
        for (int q = 0; q < 4; q++) {
            int d = d4[q];
            if (d < dlo || d >= dhi) continue;
            int pos = atomicAdd(&count[d], 1);
            if (pos < CAP) srcs[d * CAP + pos] = s4[q];
        }
    }
}

// ---- K5: softmax-aggregate + bias + leaky_relu + FUSED max-pool ----
// 8-way-parallel gather (8 sources x 8 channel-octets per wave, full MLP),
// all reductions on VALU (DPP butterflies), broadcasts via readlane.
__global__ __launch_bounds__(192) void k_aggr(const int* __restrict__ count,
        const int* __restrict__ srcs, const float* __restrict__ asrc,
        const float* __restrict__ adst, const ushort_t* __restrict__ hb,
        const float* __restrict__ bias, const int* __restrict__ batch,
        unsigned* __restrict__ pooled) {
    __shared__ float sm[HIDDEN];
    const int n0 = blockIdx.x * GAGG;
    const int tid = threadIdx.x;
    const int head = tid >> 6, lane = tid & 63;
    // source-slot = lane bits {0,1,3}; channel-octet = lane bits {2,4,5}
    const int srci = (lane & 3) | ((lane >> 1) & 4);
    const int slot = ((lane >> 2) & 1) | ((lane >> 3) & 6);
    const char* hbase = (const char*)hb + head * 128 + slot * 16;
    const int c0 = head * HEAD_DIM + slot * 8;

    // per-block preloads (amortized over GAGG nodes)
    int cntv = (lane < GAGG) ? count[n0 + lane] : 0;
    int bgv  = (lane < GAGG) ? batch[n0 + lane] : 0;
    float adv = (lane < GAGG * HEADS) ? adst[n0 * HEADS + lane] : 0.f;
    float bv[8];
#pragma unroll
    for (int k = 0; k < 8; k++) bv[k] = bias[c0 + k];

    float vmax[8];
#pragma unroll
    for (int k = 0; k < 8; k++) vmax[k] = -INFINITY;
    int curg = rl_i(bgv, 0);

    for (int g = 0; g < GAGG; g++) {
        const int gg = rl_i(bgv, g);           // uniform (batch sorted)
        if (gg != curg) {                      // block-uniform graph boundary
            if ((lane & 11) == 0) {            // one owner lane per octet
#pragma unroll
                for (int k = 0; k < 8; k++) sm[c0 + k] = vmax[k];
            }
            __syncthreads();
            atomicMax(&pooled[curg * HIDDEN + tid], f2ord(sm[tid]));
            __syncthreads();
#pragma unroll
            for (int k = 0; k < 8; k++) vmax[k] = -INFINITY;
            curg = gg;
        }

        int cnt = rl_i(cntv, g);
        if (cnt > CAP) cnt = CAP;
        const float ad = rl_f(adv, g * HEADS + head);
        const int n = n0 + g;

        int s = 0; float myexp = 0.f; int myoff = 0;
        if (lane < cnt) {                      // exec-masked bucket read:
            s = srcs[n * CAP + lane];          // only ~cnt/16 sectors fetched
            float e = asrc[s * HEADS + head] + ad;
            e = (e > 0.f) ? e : 0.2f * e;      // leaky_relu slope 0.2
            myexp = expf(e);                   // max-free softmax numerator
            myoff = s * (HIDDEN * 2);
        }

        float acc[8];
#pragma unroll
        for (int k = 0; k < 8; k++) acc[k] = 0.f;
        float dpart = 0.f;
        int groups = (cnt + 7) >> 3;
#pragma unroll 2
        for (int j = 0; j < groups; j++) {
            int sl = j * 8 + srci;
            float a   = __shfl(myexp, sl);     // 0 for padded edges
            int   off = __shfl(myoff, sl);
            uint4 u = *(const uint4*)(hbase + off);
            acc[0] += a * __uint_as_float(u.x << 16);
            acc[1] += a * __uint_as_float(u.x & 0xffff0000u);
            acc[2] += a * __uint_as_float(u.y << 16);
            acc[3] += a * __uint_as_float(u.y & 0xffff0000u);
            acc[4] += a * __uint_as_float(u.z << 16);
            acc[5] += a * __uint_as_float(u.z & 0xffff0000u);
            acc[6] += a * __uint_as_float(u.w << 16);
            acc[7] += a * __uint_as_float(u.w & 0xffff0000u);
            dpart += a;
        }

        // VALU butterfly over lane bits {0,1,3}: sums the 8 source-slots
        dpart = bfly<DPP_XOR1>(dpart);
        dpart = bfly<DPP_XOR2>(dpart);
        dpart = bfly<DPP_XOR8>(dpart);
#pragma unroll
        for (int k = 0; k < 8; k++) {
            acc[k] = bfly<DPP_XOR1>(acc[k]);
            acc[k] = bfly<DPP_XOR2>(acc[k]);
            acc[k] = bfly<DPP_XOR8>(acc[k]);
        }

        const float inv = 1.f / dpart;
#pragma unroll
        for (int k = 0; k < 8; k++) {          // all lanes (redundant, branchless)
            float v = acc[k] * inv + bv[k];
            v = (v > 0.f) ? v : 0.01f * v;     // F.leaky_relu slope 0.01
            vmax[k] = fmaxf(vmax[k], v);
        }
    }

    // final flush
    if ((lane & 11) == 0) {
#pragma unroll
        for (int k = 0; k < 8; k++) sm[c0 + k] = vmax[k];
    }
    __syncthreads();
    atomicMax(&pooled[curg * HIDDEN + tid], f2ord(sm[tid]));
}

// ---- K6: classifier, block per graph, lane-parallel dot + reduce ----
__global__ __launch_bounds__(64) void k_cls(const unsigned* __restrict__ pooled,
        const float* __restrict__ clsW, const float* __restrict__ clsb,
        float* __restrict__ out) {
    const int g = blockIdx.x, lane = threadIdx.x;
    float s0 = 0.f, s1 = 0.f;
#pragma unroll
    for (int i = 0; i < 3; i++) {
        int f = i * 64 + lane;
        float pv = ord2f(pooled[g * HIDDEN + f]);
        s0 += pv * clsW[f * NUM_CLASSES];
        s1 += pv * clsW[f * NUM_CLASSES + 1];
    }
#pragma unroll
    for (int m = 1; m < 64; m <<= 1) {
        s0 += __shfl_xor(s0, m);
        s1 += __shfl_xor(s1, m);
    }
    if (lane == 0) {
        out[g * NUM_CLASSES]     = s0 + clsb[0];
        out[g * NUM_CLASSES + 1] = s1 + clsb[1];
    }
}

extern "C" void kernel_launch(void* const* d_in, const int* in_sizes, int n_in,
                              void* d_out, int out_size, void* d_ws, size_t ws_size,
                              hipStream_t stream) {
    const float* x       = (const float*)d_in[0];
    const int*   ei      = (const int*)d_in[1];   // [2, N_EDGES] flat
    const int*   batch   = (const int*)d_in[2];
    const float* W       = (const float*)d_in[3];
    const float* att_src = (const float*)d_in[4];
    const float* att_dst = (const float*)d_in[5];
    const float* bias    = (const float*)d_in[6];
    const float* clsW    = (const float*)d_in[7];
    const float* clsb    = (const float*)d_in[8];
    float* out = (float*)d_out;

    char* p = (char*)d_ws;
    auto alloc = [&](size_t bytes) {
        char* r = p; p += (bytes + 255) & ~size_t(255); return r;
    };
    ushort_t* hb     = (ushort_t*)alloc(sizeof(ushort_t) * N_NODES * HIDDEN);
    float*    asrc   = (float*)   alloc(sizeof(float) * N_NODES * HEADS);
    float*    adst   = (float*)   alloc(sizeof(float) * N_NODES * HEADS);
    int*      count  = (int*)     alloc(sizeof(int) * N_NODES);
    int*      srcs   = (int*)     alloc(sizeof(int) * (size_t)N_NODES * CAP);
    ushort_t* WT_hi  = (ushort_t*)alloc(sizeof(ushort_t) * WT_COLS * KPAD);
    ushort_t* WT_lo  = (ushort_t*)alloc(sizeof(ushort_t) * WT_COLS * KPAD);
    unsigned* pooled = (unsigned*)alloc(sizeof(unsigned) * NUM_GRAPHS * HIDDEN);

    hipMemsetAsync(count, 0, sizeof(int) * N_NODES, stream);
    hipMemsetAsync(pooled, 0, sizeof(unsigned) * NUM_GRAPHS * HIDDEN, stream);

    k_prep<<<WT_COLS / 8, 256, 0, stream>>>(W, att_src, att_dst, WT_hi, WT_lo);
    k_gemm<<<NGEMM, 256, 0, stream>>>(x, WT_hi, WT_lo, hb, asrc, adst);
    k_scat<<<SCAT_BLKS, 256, 0, stream>>>(ei, count, srcs);
    k_aggr<<<N_NODES / GAGG, 192, 0, stream>>>(count, srcs, asrc, adst, hb, bias,
                                               batch, pooled);
    k_cls<<<NUM_GRAPHS, 64, 0, stream>>>(pooled, clsW, clsb, out);
}